// Round 1
// baseline (99.534 us; speedup 1.0000x reference)
//
#include <hip/hip_runtime.h>
#include <hip/hip_bf16.h>
#include <stdint.h>

#define N_ATOMS 131072
#define D_IN    128
#define D_HID   256
#define N_ELEM  4
// each element bucket padded to a multiple of 64 (one wave's atom tile)
#define NPAD    (N_ATOMS + N_ELEM * 64)   // 131328 slots max

typedef __attribute__((ext_vector_type(8))) short bf16x8;
typedef __attribute__((ext_vector_type(4))) float f32x4;

// ws layout (bytes):
//   [0,       262144): W1t bf16  [4][256][128]  (h-major, k contiguous)
//   [262144,  262160): counts[4]
//   [262160,  262180): start[5]  (bucket starts, 64-aligned; start[4]=padded total)
//   [262208,  262224): cursor[4]
//   [262272,  ...   ): sortedIdx[NPAD] int
#define WS_COUNTS 262144
#define WS_START  262160
#define WS_CURSOR 262208
#define WS_SIDX   262272

__device__ __forceinline__ unsigned short f2bf(float f) {
    union { float f; unsigned u; } v; v.f = f;
    unsigned r = v.u + 0x7FFFu + ((v.u >> 16) & 1u);   // RNE
    return (unsigned short)(r >> 16);
}

// K1: histogram element ids (block-aggregated) + transpose-convert W1 -> W1t bf16.
// Note 4*128*256 == 131072 == N_ATOMS, so one index space covers both jobs.
__global__ void tnn_k1_hist_w1t(const int* __restrict__ eid, int* __restrict__ counts,
                                const float* __restrict__ W1, unsigned short* __restrict__ W1t) {
    __shared__ int lc[N_ELEM];
    int t = threadIdx.x;
    if (t < N_ELEM) lc[t] = 0;
    __syncthreads();
    int i = blockIdx.x * blockDim.x + t;
    if (i < N_ATOMS) {
        atomicAdd(&lc[eid[i]], 1);
        // W1 flat index i = ((e*128)+k)*256 + h   ->  W1t[((e*256)+h)*128 + k]
        int e   = i >> 15;        // / (128*256)
        int rem = i & 32767;
        int k   = rem >> 8;
        int h   = rem & 255;
        W1t[(((e << 8) + h) << 7) + k] = (unsigned short)f2bf(W1[i]);
    }
    __syncthreads();
    if (t < N_ELEM && lc[t]) atomicAdd(&counts[t], lc[t]);
}

// K2: bucket starts (64-aligned) + analytic b2 contribution into d_out[0].
__global__ void tnn_k2_offsets(const int* __restrict__ counts, int* __restrict__ startArr,
                               const float* __restrict__ b2, float* __restrict__ out) {
    if (threadIdx.x == 0 && blockIdx.x == 0) {
        int s = 0;
        float acc = 0.f;
        for (int e = 0; e < N_ELEM; ++e) {
            startArr[e] = s;
            s += (counts[e] + 63) & ~63;
            acc += (float)counts[e] * b2[e];   // b2 is [E,1]
        }
        startArr[N_ELEM] = s;
        out[0] = acc;
    }
}

// K3: counting-sort scatter (block-aggregated cursors).
__global__ void tnn_k3_scatter(const int* __restrict__ eid, const int* __restrict__ startArr,
                               int* __restrict__ cursor, int* __restrict__ sortedIdx) {
    __shared__ int lc[N_ELEM];
    __shared__ int lbase[N_ELEM];
    int t = threadIdx.x;
    if (t < N_ELEM) lc[t] = 0;
    __syncthreads();
    int i = blockIdx.x * blockDim.x + t;
    int e = 0, rank = 0;
    bool valid = (i < N_ATOMS);
    if (valid) {
        e = eid[i];
        rank = atomicAdd(&lc[e], 1);
    }
    __syncthreads();
    if (t < N_ELEM) lbase[t] = atomicAdd(&cursor[t], lc[t]);
    __syncthreads();
    if (valid) sortedIdx[startArr[e] + lbase[e] + rank] = i;
}

// K4: per-wave 64-atom tile. A (descriptors, bf16) fully register-resident;
// B (W1t) streamed from L2; epilogue tanh(acc+b1)*w2 -> scalar partial.
__global__ __launch_bounds__(256) void tnn_k4_mlp(
        const float* __restrict__ X, const int* __restrict__ sortedIdx,
        const int* __restrict__ startArr, const int* __restrict__ counts,
        const unsigned short* __restrict__ W1t, const float* __restrict__ b1,
        const float* __restrict__ W2, float* __restrict__ out) {
    int wid  = threadIdx.x >> 6;
    int lane = threadIdx.x & 63;
    int waveBase = (blockIdx.x * 4 + wid) << 6;
    int total = startArr[N_ELEM];
    if (waveBase >= total) return;               // wave-uniform

    int e = 0;
    while (waveBase >= startArr[e + 1]) ++e;     // wave-uniform, e in [0,4)
    int realEnd = startArr[e] + counts[e];

    int l15 = lane & 15;
    int lk  = lane >> 4;

    // ---- stage A fragments: 64 atoms x 128 k, bf16, in registers ----
    bf16x8 a[4][4];
    #pragma unroll
    for (int m = 0; m < 4; ++m) {
        int slot = waveBase + m * 16 + l15;
        int row  = (slot < realEnd) ? sortedIdx[slot] : 0;   // clamp padded slots
        const float* xr = X + (size_t)row * D_IN + lk * 8;
        #pragma unroll
        for (int ks = 0; ks < 4; ++ks) {
            f32x4 v0 = *(const f32x4*)(xr + ks * 32);
            f32x4 v1 = *(const f32x4*)(xr + ks * 32 + 4);
            bf16x8 tv;
            tv[0] = (short)f2bf(v0[0]); tv[1] = (short)f2bf(v0[1]);
            tv[2] = (short)f2bf(v0[2]); tv[3] = (short)f2bf(v0[3]);
            tv[4] = (short)f2bf(v1[0]); tv[5] = (short)f2bf(v1[1]);
            tv[6] = (short)f2bf(v1[2]); tv[7] = (short)f2bf(v1[3]);
            a[m][ks] = tv;
        }
    }

    const unsigned short* w1e = W1t + (size_t)e * D_HID * D_IN;
    const float* b1e = b1 + e * D_HID;
    const float* w2e = W2 + e * D_HID;   // W2 is [E,256,1]
    float partial = 0.f;

    for (int nt = 0; nt < 16; ++nt) {
        int h = nt * 16 + l15;
        const unsigned short* wr = w1e + (size_t)h * D_IN + lk * 8;
        bf16x8 b[4];
        #pragma unroll
        for (int ks = 0; ks < 4; ++ks)
            b[ks] = *(const bf16x8*)(wr + ks * 32);
        float b1v = b1e[h];
        float w2v = w2e[h];

        #pragma unroll
        for (int m = 0; m < 4; ++m) {
            f32x4 acc = {0.f, 0.f, 0.f, 0.f};
            #pragma unroll
            for (int ks = 0; ks < 4; ++ks)
                acc = __builtin_amdgcn_mfma_f32_16x16x32_bf16(a[m][ks], b[ks], acc, 0, 0, 0);
            int rowBase = waveBase + m * 16 + lk * 4;
            #pragma unroll
            for (int r = 0; r < 4; ++r) {
                if (rowBase + r < realEnd) {
                    float pre = acc[r] + b1v;
                    float th  = 1.f - 2.f / (__expf(2.f * pre) + 1.f);
                    partial += th * w2v;
                }
            }
        }
    }

    // wave reduce + one atomic per wave
    #pragma unroll
    for (int off = 32; off; off >>= 1)
        partial += __shfl_down(partial, off);
    if (lane == 0) atomicAdd(out, partial);
}

extern "C" void kernel_launch(void* const* d_in, const int* in_sizes, int n_in,
                              void* d_out, int out_size, void* d_ws, size_t ws_size,
                              hipStream_t stream) {
    const float* X   = (const float*)d_in[0];
    const int*   eid = (const int*)  d_in[1];
    const float* W1  = (const float*)d_in[2];
    const float* b1  = (const float*)d_in[3];
    const float* W2  = (const float*)d_in[4];
    const float* b2  = (const float*)d_in[5];
    float* out = (float*)d_out;

    char* ws = (char*)d_ws;
    unsigned short* W1t = (unsigned short*)ws;
    int* counts    = (int*)(ws + WS_COUNTS);
    int* startArr  = (int*)(ws + WS_START);
    int* cursor    = (int*)(ws + WS_CURSOR);
    int* sortedIdx = (int*)(ws + WS_SIDX);

    // zero counts/start/cursor region
    hipMemsetAsync(ws + WS_COUNTS, 0, 128, stream);

    hipLaunchKernelGGL(tnn_k1_hist_w1t, dim3(512), dim3(256), 0, stream, eid, counts, W1, W1t);
    hipLaunchKernelGGL(tnn_k2_offsets, dim3(1), dim3(64), 0, stream, counts, startArr, b2, out);
    hipLaunchKernelGGL(tnn_k3_scatter, dim3(512), dim3(256), 0, stream, eid, startArr, cursor, sortedIdx);
    hipLaunchKernelGGL(tnn_k4_mlp, dim3(NPAD / 256), dim3(256), 0, stream,
                       X, sortedIdx, startArr, counts, W1t, b1, W2, out);
}

// Round 2
// 74.240 us; speedup vs baseline: 1.3407x; 1.3407x over previous
//
#include <hip/hip_runtime.h>
#include <hip/hip_bf16.h>
#include <stdint.h>

#define N_ATOMS 131072
#define D_IN    128
#define D_HID   256
#define N_ELEM  4
// each element bucket padded to a multiple of 64 (one wave's atom tile)
#define NPAD    (N_ATOMS + N_ELEM * 64)   // 131328 slots max
#define NTILES  (NPAD / 64)               // 2052

typedef __attribute__((ext_vector_type(8))) short bf16x8;
typedef __attribute__((ext_vector_type(4))) float f32x4;

// ws layout (bytes):
//   [0,       262144): W1t bf16  [4][256][128]  (h-major, k contiguous)
//   [262144,  262160): counts[4]
//   [262160,  262180): start[5]  (bucket starts, 64-aligned; start[4]=padded total)
//   [262208,  262224): cursor[4]
//   [262272,  ...   ): sortedIdx[NPAD] int
#define WS_COUNTS 262144
#define WS_START  262160
#define WS_CURSOR 262208
#define WS_SIDX   262272

__device__ __forceinline__ unsigned short f2bf_rne(float f) {
    union { float f; unsigned u; } v; v.f = f;
    unsigned r = v.u + 0x7FFFu + ((v.u >> 16) & 1u);   // RNE
    return (unsigned short)(r >> 16);
}

// K1: histogram element ids (block-aggregated) + transpose-convert W1 -> W1t bf16.
// Note 4*128*256 == 131072 == N_ATOMS, so one index space covers both jobs.
__global__ void tnn_k1_hist_w1t(const int* __restrict__ eid, int* __restrict__ counts,
                                const float* __restrict__ W1, unsigned short* __restrict__ W1t) {
    __shared__ int lc[N_ELEM];
    int t = threadIdx.x;
    if (t < N_ELEM) lc[t] = 0;
    __syncthreads();
    int i = blockIdx.x * blockDim.x + t;
    if (i < N_ATOMS) {
        atomicAdd(&lc[eid[i]], 1);
        // W1 flat index i = ((e*128)+k)*256 + h   ->  W1t[((e*256)+h)*128 + k]
        int e   = i >> 15;        // / (128*256)
        int rem = i & 32767;
        int k   = rem >> 8;
        int h   = rem & 255;
        W1t[(((e << 8) + h) << 7) + k] = f2bf_rne(W1[i]);
    }
    __syncthreads();
    if (t < N_ELEM && lc[t]) atomicAdd(&counts[t], lc[t]);
}

// K2: bucket starts (64-aligned) + analytic b2 contribution into d_out[0].
__global__ void tnn_k2_offsets(const int* __restrict__ counts, int* __restrict__ startArr,
                               const float* __restrict__ b2, float* __restrict__ out) {
    if (threadIdx.x == 0 && blockIdx.x == 0) {
        int s = 0;
        float acc = 0.f;
        for (int e = 0; e < N_ELEM; ++e) {
            startArr[e] = s;
            s += (counts[e] + 63) & ~63;
            acc += (float)counts[e] * b2[e];   // b2 is [E,1]
        }
        startArr[N_ELEM] = s;
        out[0] = acc;
    }
}

// K3: counting-sort scatter (block-aggregated cursors).
__global__ void tnn_k3_scatter(const int* __restrict__ eid, const int* __restrict__ startArr,
                               int* __restrict__ cursor, int* __restrict__ sortedIdx) {
    __shared__ int lc[N_ELEM];
    __shared__ int lbase[N_ELEM];
    int t = threadIdx.x;
    if (t < N_ELEM) lc[t] = 0;
    __syncthreads();
    int i = blockIdx.x * blockDim.x + t;
    int e = 0, rank = 0;
    bool valid = (i < N_ATOMS);
    if (valid) {
        e = eid[i];
        rank = atomicAdd(&lc[e], 1);
    }
    __syncthreads();
    if (t < N_ELEM) lbase[t] = atomicAdd(&cursor[t], lc[t]);
    __syncthreads();
    if (valid) sortedIdx[startArr[e] + lbase[e] + rank] = i;
}

// ---- K4 helper: one wave processes 64 atoms x 128 hidden (half of D_HID) ----
template<bool FULL>
__device__ __forceinline__ float wave_tile(
        const float* __restrict__ X, const int* __restrict__ sortedIdx,
        int waveBase, int realEnd,
        const unsigned short* __restrict__ w1e, const float* __restrict__ b1e,
        const float* __restrict__ w2e, int half, int lane) {
    const float C2 = 2.8853900817779268f;   // 2*log2(e)
    int l15 = lane & 15;
    int lk  = lane >> 4;

    // ---- A fragments: 64 atoms x 128 k, bf16 (truncated), register-resident ----
    bf16x8 a[4][4];
    #pragma unroll
    for (int m = 0; m < 4; ++m) {
        int slot = waveBase + m * 16 + l15;
        int row;
        if (FULL) row = sortedIdx[slot];
        else      row = (slot < realEnd) ? sortedIdx[slot] : sortedIdx[waveBase];
        const float* xr = X + (size_t)row * D_IN + lk * 8;
        #pragma unroll
        for (int ks = 0; ks < 4; ++ks) {
            f32x4 v0 = *(const f32x4*)(xr + ks * 32);
            f32x4 v1 = *(const f32x4*)(xr + ks * 32 + 4);
            bf16x8 tv;
            tv[0] = (short)(__float_as_uint(v0[0]) >> 16);
            tv[1] = (short)(__float_as_uint(v0[1]) >> 16);
            tv[2] = (short)(__float_as_uint(v0[2]) >> 16);
            tv[3] = (short)(__float_as_uint(v0[3]) >> 16);
            tv[4] = (short)(__float_as_uint(v1[0]) >> 16);
            tv[5] = (short)(__float_as_uint(v1[1]) >> 16);
            tv[6] = (short)(__float_as_uint(v1[2]) >> 16);
            tv[7] = (short)(__float_as_uint(v1[3]) >> 16);
            a[m][ks] = tv;
        }
    }

    // valid-row count per lane (same for every nt)
    float fnval = 16.f;
    if (!FULL) {
        int nv = 0;
        #pragma unroll
        for (int m = 0; m < 4; ++m)
            #pragma unroll
            for (int r = 0; r < 4; ++r)
                nv += (waveBase + m * 16 + lk * 4 + r < realEnd) ? 1 : 0;
        fnval = (float)nv;
    }

    const unsigned short* wr = w1e + (size_t)(half * 128 + l15) * D_IN + lk * 8;
    const float* b1p = b1e + half * 128 + l15;
    const float* w2p = w2e + half * 128 + l15;

    bf16x8 cur[4], nxt[4];
    #pragma unroll
    for (int ks = 0; ks < 4; ++ks) cur[ks] = *(const bf16x8*)(wr + ks * 32);
    float b1v = b1p[0], w2v = w2p[0];

    float partial = 0.f;
    #pragma unroll
    for (int nt = 0; nt < 8; ++nt) {
        // prefetch next h-group's B fragments + scalars (dup load at nt==7, harmless)
        int ntn = (nt < 7) ? nt + 1 : 7;
        const unsigned short* wrn = wr + (size_t)ntn * 16 * D_IN;
        #pragma unroll
        for (int ks = 0; ks < 4; ++ks) nxt[ks] = *(const bf16x8*)(wrn + ks * 32);
        float b1n = b1p[ntn * 16];
        float w2n = w2p[ntn * 16];

        f32x4 acc[4];
        #pragma unroll
        for (int m = 0; m < 4; ++m) {
            acc[m] = f32x4{0.f, 0.f, 0.f, 0.f};
            #pragma unroll
            for (int ks = 0; ks < 4; ++ks)
                acc[m] = __builtin_amdgcn_mfma_f32_16x16x32_bf16(a[m][ks], cur[ks], acc[m], 0, 0, 0);
        }

        // tanh(p) = 1 - 2/(exp2(C2*p)+1);  sum w2*tanh = w2*(nval - 2*sum(rcp))
        float b1s = b1v * C2;
        float rsum = 0.f;
        #pragma unroll
        for (int m = 0; m < 4; ++m) {
            #pragma unroll
            for (int r = 0; r < 4; ++r) {
                float ex = __builtin_amdgcn_exp2f(fmaf(C2, acc[m][r], b1s));
                float rc = __builtin_amdgcn_rcpf(ex + 1.f);
                if (!FULL)
                    rc = (waveBase + m * 16 + lk * 4 + r < realEnd) ? rc : 0.f;
                rsum += rc;
            }
        }
        partial = fmaf(w2v, fmaf(-2.f, rsum, fnval), partial);

        #pragma unroll
        for (int ks = 0; ks < 4; ++ks) cur[ks] = nxt[ks];
        b1v = b1n; w2v = w2n;
    }
    return partial;
}

// K4: 4 waves/block; waves (tile, half) = (blockIdx*2 + wid/2, wid&1).
__global__ __launch_bounds__(256, 4) void tnn_k4_mlp(
        const float* __restrict__ X, const int* __restrict__ sortedIdx,
        const int* __restrict__ startArr, const int* __restrict__ counts,
        const unsigned short* __restrict__ W1t, const float* __restrict__ b1,
        const float* __restrict__ W2, float* __restrict__ out) {
    __shared__ float red[4];
    int wid  = threadIdx.x >> 6;
    int lane = threadIdx.x & 63;
    int tile = blockIdx.x * 2 + (wid >> 1);
    int half = wid & 1;
    int waveBase = tile << 6;
    int total = startArr[N_ELEM];

    float partial = 0.f;
    if (waveBase < total) {
        int e = 0;
        while (waveBase >= startArr[e + 1]) ++e;     // wave-uniform
        int realEnd = startArr[e] + counts[e];
        const unsigned short* w1e = W1t + (size_t)e * D_HID * D_IN;
        const float* b1e = b1 + e * D_HID;
        const float* w2e = W2 + e * D_HID;           // W2 is [E,256,1]
        if (waveBase + 64 <= realEnd)
            partial = wave_tile<true >(X, sortedIdx, waveBase, realEnd, w1e, b1e, w2e, half, lane);
        else
            partial = wave_tile<false>(X, sortedIdx, waveBase, realEnd, w1e, b1e, w2e, half, lane);
    }

    #pragma unroll
    for (int off = 32; off; off >>= 1)
        partial += __shfl_down(partial, off);
    if (lane == 0) red[wid] = partial;
    __syncthreads();
    if (threadIdx.x == 0)
        atomicAdd(out, red[0] + red[1] + red[2] + red[3]);
}

extern "C" void kernel_launch(void* const* d_in, const int* in_sizes, int n_in,
                              void* d_out, int out_size, void* d_ws, size_t ws_size,
                              hipStream_t stream) {
    const float* X   = (const float*)d_in[0];
    const int*   eid = (const int*)  d_in[1];
    const float* W1  = (const float*)d_in[2];
    const float* b1  = (const float*)d_in[3];
    const float* W2  = (const float*)d_in[4];
    const float* b2  = (const float*)d_in[5];
    float* out = (float*)d_out;

    char* ws = (char*)d_ws;
    unsigned short* W1t = (unsigned short*)ws;
    int* counts    = (int*)(ws + WS_COUNTS);
    int* startArr  = (int*)(ws + WS_START);
    int* cursor    = (int*)(ws + WS_CURSOR);
    int* sortedIdx = (int*)(ws + WS_SIDX);

    // zero counts/start/cursor region
    hipMemsetAsync(ws + WS_COUNTS, 0, 128, stream);

    hipLaunchKernelGGL(tnn_k1_hist_w1t, dim3(512), dim3(256), 0, stream, eid, counts, W1, W1t);
    hipLaunchKernelGGL(tnn_k2_offsets, dim3(1), dim3(64), 0, stream, counts, startArr, b2, out);
    hipLaunchKernelGGL(tnn_k3_scatter, dim3(512), dim3(256), 0, stream, eid, startArr, cursor, sortedIdx);
    hipLaunchKernelGGL(tnn_k4_mlp, dim3((NTILES + 1) / 2), dim3(256), 0, stream,
                       X, sortedIdx, startArr, counts, W1t, b1, W2, out);
}

// Round 3
// 72.775 us; speedup vs baseline: 1.3677x; 1.0201x over previous
//
#include <hip/hip_runtime.h>
#include <hip/hip_bf16.h>
#include <stdint.h>

#define N_ATOMS 131072
#define D_IN    128
#define D_HID   256
#define N_ELEM  4
// each element bucket padded to a multiple of 64 (one wave's atom tile)
#define NPAD    (N_ATOMS + N_ELEM * 64)   // 131328 slots max
#define NTILES  (NPAD / 64)               // 2052
#define K1_BLOCKS 512                      // 512*256 == N_ATOMS exactly

typedef __attribute__((ext_vector_type(8))) short bf16x8;
typedef __attribute__((ext_vector_type(4))) float f32x4;

// ws layout (bytes):
//   [0,       262144): W1t bf16 [4][256][128] (h-major, k contiguous)
//   [262144,  262160): counts[4]
//   [262176,  262200): startArr[5] (64-aligned bucket starts; [4]=padded total)
//   [262272,  270480): blockPartials[NTILES] float
//   [270592,  278784): blockCounts[512][4] int
//   [278784,  286976): blockOff[512][4] int (scatter bases, deterministic)
//   [287232,  812544): sortedIdx[NPAD] int
#define WS_COUNTS 262144
#define WS_START  262176
#define WS_BPART  262272
#define WS_BCNT   270592
#define WS_BOFF   278784
#define WS_SIDX   287232

__device__ __forceinline__ unsigned short f2bf_rne(float f) {
    union { float f; unsigned u; } v; v.f = f;
    unsigned r = v.u + 0x7FFFu + ((v.u >> 16) & 1u);   // RNE
    return (unsigned short)(r >> 16);
}

// K1: per-block histogram (plain stores, no global atomics) + W1 -> W1t bf16.
// 4*128*256 == 131072 == N_ATOMS, one index space covers both jobs.
__global__ void tnn_k1_hist_w1t(const int* __restrict__ eid, int* __restrict__ bcnt,
                                const float* __restrict__ W1, unsigned short* __restrict__ W1t) {
    __shared__ int lc[N_ELEM];
    int t = threadIdx.x;
    if (t < N_ELEM) lc[t] = 0;
    __syncthreads();
    int i = blockIdx.x * 256 + t;          // always < N_ATOMS
    atomicAdd(&lc[eid[i]], 1);             // LDS atomic only
    // W1 flat index i = ((e*128)+k)*256 + h  ->  W1t[((e*256)+h)*128 + k]
    int e   = i >> 15;
    int rem = i & 32767;
    int k   = rem >> 8;
    int h   = rem & 255;
    W1t[(((e << 8) + h) << 7) + k] = f2bf_rne(W1[i]);
    __syncthreads();
    if (t < N_ELEM) bcnt[blockIdx.x * 4 + t] = lc[t];
}

// K2: one block. Parallel scan of blockCounts -> counts, startArr, blockOff.
__global__ void tnn_k2_scan(const int* __restrict__ bcnt, int* __restrict__ counts,
                            int* __restrict__ startArr, int* __restrict__ boff) {
    __shared__ int4 sc[256];
    int t = threadIdx.x;
    int4 c0 = ((const int4*)bcnt)[2 * t];
    int4 c1 = ((const int4*)bcnt)[2 * t + 1];
    int4 ps = {c0.x + c1.x, c0.y + c1.y, c0.z + c1.z, c0.w + c1.w};
    sc[t] = ps;
    __syncthreads();
    // Hillis-Steele inclusive scan over 256 pair-sums
    #pragma unroll
    for (int off = 1; off < 256; off <<= 1) {
        int4 v = sc[t];
        int4 u = {0, 0, 0, 0};
        if (t >= off) u = sc[t - off];
        __syncthreads();
        v.x += u.x; v.y += u.y; v.z += u.z; v.w += u.w;
        sc[t] = v;
        __syncthreads();
    }
    int4 tot = sc[255];
    int st0 = 0;
    int st1 = st0 + ((tot.x + 63) & ~63);
    int st2 = st1 + ((tot.y + 63) & ~63);
    int st3 = st2 + ((tot.z + 63) & ~63);
    int st4 = st3 + ((tot.w + 63) & ~63);
    int4 incl = sc[t];
    int4 ex = {incl.x - ps.x, incl.y - ps.y, incl.z - ps.z, incl.w - ps.w};  // exclusive
    int4 o0 = {st0 + ex.x, st1 + ex.y, st2 + ex.z, st3 + ex.w};
    int4 o1 = {o0.x + c0.x, o0.y + c0.y, o0.z + c0.z, o0.w + c0.w};
    ((int4*)boff)[2 * t]     = o0;
    ((int4*)boff)[2 * t + 1] = o1;
    if (t == 0) {
        ((int4*)counts)[0] = tot;
        startArr[0] = st0; startArr[1] = st1; startArr[2] = st2;
        startArr[3] = st3; startArr[4] = st4;
    }
}

// K3: scatter with deterministic per-block bases (LDS rank atomics only).
__global__ void tnn_k3_scatter(const int* __restrict__ eid, const int* __restrict__ boff,
                               int* __restrict__ sortedIdx) {
    __shared__ int lc[N_ELEM];
    int t = threadIdx.x;
    if (t < N_ELEM) lc[t] = 0;
    __syncthreads();
    int i = blockIdx.x * 256 + t;          // always < N_ATOMS
    int e = eid[i];
    int rank = atomicAdd(&lc[e], 1);
    sortedIdx[boff[blockIdx.x * 4 + e] + rank] = i;
}

// ---- K4 helper: one wave = 64 atoms x 64 hidden (quarter of D_HID) ----
template<bool FULL>
__device__ __forceinline__ float wave_tile(
        const float* __restrict__ X, const int* __restrict__ sortedIdx,
        int waveBase, int realEnd,
        const unsigned short* __restrict__ w1e, const float* __restrict__ b1e,
        const float* __restrict__ w2e, int quarter, int lane) {
    const float C2 = 2.8853900817779268f;   // 2*log2(e)
    int l15 = lane & 15;
    int lk  = lane >> 4;

    // ---- A fragments: 64 atoms x 128 k, bf16 (truncated), register-resident ----
    bf16x8 a[4][4];
    #pragma unroll
    for (int m = 0; m < 4; ++m) {
        int slot = waveBase + m * 16 + l15;
        int row;
        if (FULL) row = sortedIdx[slot];
        else      row = (slot < realEnd) ? sortedIdx[slot] : sortedIdx[waveBase];
        const float* xr = X + (size_t)row * D_IN + lk * 8;
        #pragma unroll
        for (int ks = 0; ks < 4; ++ks) {
            f32x4 v0 = *(const f32x4*)(xr + ks * 32);
            f32x4 v1 = *(const f32x4*)(xr + ks * 32 + 4);
            bf16x8 tv;
            tv[0] = (short)(__float_as_uint(v0[0]) >> 16);
            tv[1] = (short)(__float_as_uint(v0[1]) >> 16);
            tv[2] = (short)(__float_as_uint(v0[2]) >> 16);
            tv[3] = (short)(__float_as_uint(v0[3]) >> 16);
            tv[4] = (short)(__float_as_uint(v1[0]) >> 16);
            tv[5] = (short)(__float_as_uint(v1[1]) >> 16);
            tv[6] = (short)(__float_as_uint(v1[2]) >> 16);
            tv[7] = (short)(__float_as_uint(v1[3]) >> 16);
            a[m][ks] = tv;
        }
    }

    float fnval = 16.f;
    if (!FULL) {
        int nv = 0;
        #pragma unroll
        for (int m = 0; m < 4; ++m)
            #pragma unroll
            for (int r = 0; r < 4; ++r)
                nv += (waveBase + m * 16 + lk * 4 + r < realEnd) ? 1 : 0;
        fnval = (float)nv;
    }

    const unsigned short* wr = w1e + (size_t)(quarter * 64 + l15) * D_IN + lk * 8;
    const float* b1p = b1e + quarter * 64 + l15;
    const float* w2p = w2e + quarter * 64 + l15;

    bf16x8 cur[4], nxt[4];
    #pragma unroll
    for (int ks = 0; ks < 4; ++ks) cur[ks] = *(const bf16x8*)(wr + ks * 32);
    float b1v = b1p[0], w2v = w2p[0];

    float partial = 0.f;
    #pragma unroll
    for (int nt = 0; nt < 4; ++nt) {
        int ntn = (nt < 3) ? nt + 1 : 3;     // dup prefetch at last iter, harmless
        const unsigned short* wrn = wr + (size_t)ntn * 16 * D_IN;
        #pragma unroll
        for (int ks = 0; ks < 4; ++ks) nxt[ks] = *(const bf16x8*)(wrn + ks * 32);
        float b1n = b1p[ntn * 16];
        float w2n = w2p[ntn * 16];

        f32x4 acc[4];
        #pragma unroll
        for (int m = 0; m < 4; ++m) {
            acc[m] = f32x4{0.f, 0.f, 0.f, 0.f};
            #pragma unroll
            for (int ks = 0; ks < 4; ++ks)
                acc[m] = __builtin_amdgcn_mfma_f32_16x16x32_bf16(a[m][ks], cur[ks], acc[m], 0, 0, 0);
        }

        // tanh(p) = 1 - 2/(exp2(C2*p)+1);  sum w2*tanh = w2*(nval - 2*sum(rcp))
        float b1s = b1v * C2;
        float rsum = 0.f;
        #pragma unroll
        for (int m = 0; m < 4; ++m) {
            #pragma unroll
            for (int r = 0; r < 4; ++r) {
                float exv = __builtin_amdgcn_exp2f(fmaf(C2, acc[m][r], b1s));
                float rc  = __builtin_amdgcn_rcpf(exv + 1.f);
                if (!FULL)
                    rc = (waveBase + m * 16 + lk * 4 + r < realEnd) ? rc : 0.f;
                rsum += rc;
            }
        }
        partial = fmaf(w2v, fmaf(-2.f, rsum, fnval), partial);

        #pragma unroll
        for (int ks = 0; ks < 4; ++ks) cur[ks] = nxt[ks];
        b1v = b1n; w2v = w2n;
    }
    return partial;
}

// K4: block = one 64-atom tile; 4 waves = 4 hidden-quarters. No global atomics.
__global__ __launch_bounds__(256, 4) void tnn_k4_mlp(
        const float* __restrict__ X, const int* __restrict__ sortedIdx,
        const int* __restrict__ startArr, const int* __restrict__ counts,
        const unsigned short* __restrict__ W1t, const float* __restrict__ b1,
        const float* __restrict__ W2, float* __restrict__ bpart) {
    __shared__ float red[4];
    int wid  = threadIdx.x >> 6;
    int lane = threadIdx.x & 63;
    int waveBase = blockIdx.x << 6;
    int total = startArr[N_ELEM];

    float partial = 0.f;
    if (waveBase < total) {
        int e = 0;
        while (waveBase >= startArr[e + 1]) ++e;     // wave-uniform
        int realEnd = startArr[e] + counts[e];
        const unsigned short* w1e = W1t + (size_t)e * D_HID * D_IN;
        const float* b1e = b1 + e * D_HID;
        const float* w2e = W2 + e * D_HID;           // W2 is [E,256,1]
        if (waveBase + 64 <= realEnd)
            partial = wave_tile<true >(X, sortedIdx, waveBase, realEnd, w1e, b1e, w2e, wid, lane);
        else
            partial = wave_tile<false>(X, sortedIdx, waveBase, realEnd, w1e, b1e, w2e, wid, lane);
    }

    #pragma unroll
    for (int off = 32; off; off >>= 1)
        partial += __shfl_down(partial, off);
    if (lane == 0) red[wid] = partial;
    __syncthreads();
    if (threadIdx.x == 0)
        bpart[blockIdx.x] = red[0] + red[1] + red[2] + red[3];   // plain store
}

// K5: single block reduces block partials + analytic bias term.
__global__ void tnn_k5_reduce(const float* __restrict__ bpart, const int* __restrict__ counts,
                              const float* __restrict__ b2, float* __restrict__ out) {
    __shared__ float r[4];
    int t = threadIdx.x;
    float s = 0.f;
    for (int i = t; i < NTILES; i += 256) s += bpart[i];
    #pragma unroll
    for (int off = 32; off; off >>= 1)
        s += __shfl_down(s, off);
    if ((t & 63) == 0) r[t >> 6] = s;
    __syncthreads();
    if (t == 0) {
        float acc = r[0] + r[1] + r[2] + r[3];
        #pragma unroll
        for (int e = 0; e < N_ELEM; ++e)
            acc += (float)counts[e] * b2[e];   // b2 is [E,1]
        out[0] = acc;
    }
}

extern "C" void kernel_launch(void* const* d_in, const int* in_sizes, int n_in,
                              void* d_out, int out_size, void* d_ws, size_t ws_size,
                              hipStream_t stream) {
    const float* X   = (const float*)d_in[0];
    const int*   eid = (const int*)  d_in[1];
    const float* W1  = (const float*)d_in[2];
    const float* b1  = (const float*)d_in[3];
    const float* W2  = (const float*)d_in[4];
    const float* b2  = (const float*)d_in[5];
    float* out = (float*)d_out;

    char* ws = (char*)d_ws;
    unsigned short* W1t = (unsigned short*)ws;
    int*   counts    = (int*)  (ws + WS_COUNTS);
    int*   startArr  = (int*)  (ws + WS_START);
    float* bpart     = (float*)(ws + WS_BPART);
    int*   bcnt      = (int*)  (ws + WS_BCNT);
    int*   boff      = (int*)  (ws + WS_BOFF);
    int*   sortedIdx = (int*)  (ws + WS_SIDX);

    hipLaunchKernelGGL(tnn_k1_hist_w1t, dim3(K1_BLOCKS), dim3(256), 0, stream, eid, bcnt, W1, W1t);
    hipLaunchKernelGGL(tnn_k2_scan,     dim3(1),         dim3(256), 0, stream, bcnt, counts, startArr, boff);
    hipLaunchKernelGGL(tnn_k3_scatter,  dim3(K1_BLOCKS), dim3(256), 0, stream, eid, boff, sortedIdx);
    hipLaunchKernelGGL(tnn_k4_mlp,      dim3(NTILES),    dim3(256), 0, stream,
                       X, sortedIdx, startArr, counts, W1t, b1, W2, bpart);
    hipLaunchKernelGGL(tnn_k5_reduce,   dim3(1),         dim3(256), 0, stream, bpart, counts, b2, out);
}

// Round 4
// 46.079 us; speedup vs baseline: 2.1601x; 1.5793x over previous
//
#include <hip/hip_runtime.h>
#include <hip/hip_bf16.h>
#include <stdint.h>

#define N_ATOMS 131072
#define D_IN    128
#define D_HID   256
#define N_ELEM  4
// each element bucket padded to a multiple of 64 (one wave's atom tile)
#define NPAD    (N_ATOMS + N_ELEM * 64)   // 131328 slots max
#define NTILES  (NPAD / 64)               // 2052
#define K1_BLOCKS 512                      // 512*256 == N_ATOMS exactly

typedef __attribute__((ext_vector_type(8))) short bf16x8;
typedef __attribute__((ext_vector_type(4))) float f32x4;

// ws layout (bytes):
//   [0,       262144): W1t bf16 [4][256][128] (h-major, k contiguous)
//   [262144,  262160): counts[4]
//   [262176,  262200): startArr[5] (64-aligned bucket starts; [4]=padded total)
//   [262272,  270480): blockPartials[NTILES] float
//   [270592,  278784): blockCounts[512][4] int
//   [278784,  286976): blockOff[512][4] int (scatter bases, deterministic)
//   [287232,  812544): sortedIdx[NPAD] int
#define WS_COUNTS 262144
#define WS_START  262176
#define WS_BPART  262272
#define WS_BCNT   270592
#define WS_BOFF   278784
#define WS_SIDX   287232

__device__ __forceinline__ unsigned short f2bf_rne(float f) {
    union { float f; unsigned u; } v; v.f = f;
    unsigned r = v.u + 0x7FFFu + ((v.u >> 16) & 1u);   // RNE
    return (unsigned short)(r >> 16);
}

// K1: per-block histogram (plain stores, no global atomics) + W1 -> W1t bf16.
// 4*128*256 == 131072 == N_ATOMS, one index space covers both jobs.
__global__ void tnn_k1_hist_w1t(const int* __restrict__ eid, int* __restrict__ bcnt,
                                const float* __restrict__ W1, unsigned short* __restrict__ W1t) {
    __shared__ int lc[N_ELEM];
    int t = threadIdx.x;
    if (t < N_ELEM) lc[t] = 0;
    __syncthreads();
    int i = blockIdx.x * 256 + t;          // always < N_ATOMS
    atomicAdd(&lc[eid[i]], 1);             // LDS atomic only
    // W1 flat index i = ((e*128)+k)*256 + h  ->  W1t[((e*256)+h)*128 + k]
    int e   = i >> 15;
    int rem = i & 32767;
    int k   = rem >> 8;
    int h   = rem & 255;
    W1t[(((e << 8) + h) << 7) + k] = f2bf_rne(W1[i]);
    __syncthreads();
    if (t < N_ELEM) bcnt[blockIdx.x * 4 + t] = lc[t];
}

// K2: one block. Parallel scan of blockCounts -> counts, startArr, blockOff.
__global__ void tnn_k2_scan(const int* __restrict__ bcnt, int* __restrict__ counts,
                            int* __restrict__ startArr, int* __restrict__ boff) {
    __shared__ int4 sc[256];
    int t = threadIdx.x;
    int4 c0 = ((const int4*)bcnt)[2 * t];
    int4 c1 = ((const int4*)bcnt)[2 * t + 1];
    int4 ps = {c0.x + c1.x, c0.y + c1.y, c0.z + c1.z, c0.w + c1.w};
    sc[t] = ps;
    __syncthreads();
    // Hillis-Steele inclusive scan over 256 pair-sums
    #pragma unroll
    for (int off = 1; off < 256; off <<= 1) {
        int4 v = sc[t];
        int4 u = {0, 0, 0, 0};
        if (t >= off) u = sc[t - off];
        __syncthreads();
        v.x += u.x; v.y += u.y; v.z += u.z; v.w += u.w;
        sc[t] = v;
        __syncthreads();
    }
    int4 tot = sc[255];
    int st0 = 0;
    int st1 = st0 + ((tot.x + 63) & ~63);
    int st2 = st1 + ((tot.y + 63) & ~63);
    int st3 = st2 + ((tot.z + 63) & ~63);
    int st4 = st3 + ((tot.w + 63) & ~63);
    int4 incl = sc[t];
    int4 ex = {incl.x - ps.x, incl.y - ps.y, incl.z - ps.z, incl.w - ps.w};  // exclusive
    int4 o0 = {st0 + ex.x, st1 + ex.y, st2 + ex.z, st3 + ex.w};
    int4 o1 = {o0.x + c0.x, o0.y + c0.y, o0.z + c0.z, o0.w + c0.w};
    ((int4*)boff)[2 * t]     = o0;
    ((int4*)boff)[2 * t + 1] = o1;
    if (t == 0) {
        ((int4*)counts)[0] = tot;
        startArr[0] = st0; startArr[1] = st1; startArr[2] = st2;
        startArr[3] = st3; startArr[4] = st4;
    }
}

// K3: scatter with deterministic per-block bases (LDS rank atomics only).
__global__ void tnn_k3_scatter(const int* __restrict__ eid, const int* __restrict__ boff,
                               int* __restrict__ sortedIdx) {
    __shared__ int lc[N_ELEM];
    int t = threadIdx.x;
    if (t < N_ELEM) lc[t] = 0;
    __syncthreads();
    int i = blockIdx.x * 256 + t;          // always < N_ATOMS
    int e = eid[i];
    int rank = atomicAdd(&lc[e], 1);
    sortedIdx[boff[blockIdx.x * 4 + e] + rank] = i;
}

// K4: block = one 64-atom tile staged in LDS (bf16, XOR-swizzled); 4 waves = 4
// hidden-quarters reading shared A-frags from LDS. No spills, no global atomics.
__global__ __launch_bounds__(256, 4) void tnn_k4_mlp(
        const float* __restrict__ X, const int* __restrict__ sortedIdx,
        const int* __restrict__ startArr, const int* __restrict__ counts,
        const unsigned short* __restrict__ W1t, const float* __restrict__ b1,
        const float* __restrict__ W2, float* __restrict__ bpart) {
    __shared__ unsigned char lds[64 * 128 * 2];   // 16 KB A-tile, swizzled
    __shared__ float red[4];
    const float C2 = 2.8853900817779268f;         // 2*log2(e)

    int t = threadIdx.x;
    int wid  = t >> 6;
    int lane = t & 63;
    int waveBase = blockIdx.x << 6;
    int total = startArr[N_ELEM];
    bool active = (waveBase < total);

    int e = 0, realEnd = 0;
    if (active) {
        while (waveBase >= startArr[e + 1]) ++e;   // uniform
        realEnd = startArr[e] + counts[e];

        // ---- cooperative stage: 64 atoms x 128 k -> LDS bf16 (swizzled) ----
        int row   = t >> 2;          // 0..63
        int chunk = t & 3;           // 0..3 (32 floats each)
        int slot  = waveBase + row;
        int g = (slot < realEnd) ? sortedIdx[slot] : sortedIdx[waveBase];
        const float* xr = X + (size_t)g * D_IN + chunk * 32;
        unsigned rowb = row * 256;
        unsigned sw   = (row & 7) << 4;
        #pragma unroll
        for (int j = 0; j < 4; ++j) {
            f32x4 v0 = *(const f32x4*)(xr + j * 8);
            f32x4 v1 = *(const f32x4*)(xr + j * 8 + 4);
            bf16x8 tv;
            tv[0] = (short)(__float_as_uint(v0[0]) >> 16);
            tv[1] = (short)(__float_as_uint(v0[1]) >> 16);
            tv[2] = (short)(__float_as_uint(v0[2]) >> 16);
            tv[3] = (short)(__float_as_uint(v0[3]) >> 16);
            tv[4] = (short)(__float_as_uint(v1[0]) >> 16);
            tv[5] = (short)(__float_as_uint(v1[1]) >> 16);
            tv[6] = (short)(__float_as_uint(v1[2]) >> 16);
            tv[7] = (short)(__float_as_uint(v1[3]) >> 16);
            *(bf16x8*)(&lds[(rowb + chunk * 64 + j * 16) ^ sw]) = tv;
        }
    }

    float partial = 0.f;
    if (active) {
        int l15 = lane & 15;
        int lk  = lane >> 4;
        bool full = (waveBase + 64 <= realEnd);

        // B pointers for this wave's hidden-quarter; issue first loads pre-barrier
        const unsigned short* wr = W1t + (size_t)e * D_HID * D_IN
                                       + (size_t)(wid * 64 + l15) * D_IN + lk * 8;
        const float* b1p = b1 + e * D_HID + wid * 64 + l15;
        const float* w2p = W2 + e * D_HID + wid * 64 + l15;
        bf16x8 cur[4], nxt[4];
        #pragma unroll
        for (int ks = 0; ks < 4; ++ks) cur[ks] = *(const bf16x8*)(wr + ks * 32);
        float b1v = b1p[0], w2v = w2p[0];

        float fnval = 16.f;
        if (!full) {
            int nv = 0;
            #pragma unroll
            for (int m = 0; m < 4; ++m)
                #pragma unroll
                for (int r = 0; r < 4; ++r)
                    nv += (waveBase + m * 16 + lk * 4 + r < realEnd) ? 1 : 0;
            fnval = (float)nv;
        }

        __syncthreads();   // A-tile ready

        #pragma unroll
        for (int nt = 0; nt < 4; ++nt) {
            int ntn = (nt < 3) ? nt + 1 : 3;     // dup prefetch last iter, harmless
            const unsigned short* wrn = wr + (size_t)ntn * 16 * D_IN;
            #pragma unroll
            for (int ks = 0; ks < 4; ++ks) nxt[ks] = *(const bf16x8*)(wrn + ks * 32);
            float b1n = b1p[ntn * 16];
            float w2n = w2p[ntn * 16];

            f32x4 acc[4];
            #pragma unroll
            for (int m = 0; m < 4; ++m) {
                int row = m * 16 + l15;
                unsigned base = row * 256 + lk * 16;
                unsigned sw2  = (row & 7) << 4;
                bf16x8 a0 = *(const bf16x8*)(&lds[(base      ) ^ sw2]);
                bf16x8 a1 = *(const bf16x8*)(&lds[(base +  64) ^ sw2]);
                bf16x8 a2 = *(const bf16x8*)(&lds[(base + 128) ^ sw2]);
                bf16x8 a3 = *(const bf16x8*)(&lds[(base + 192) ^ sw2]);
                acc[m] = f32x4{0.f, 0.f, 0.f, 0.f};
                acc[m] = __builtin_amdgcn_mfma_f32_16x16x32_bf16(a0, cur[0], acc[m], 0, 0, 0);
                acc[m] = __builtin_amdgcn_mfma_f32_16x16x32_bf16(a1, cur[1], acc[m], 0, 0, 0);
                acc[m] = __builtin_amdgcn_mfma_f32_16x16x32_bf16(a2, cur[2], acc[m], 0, 0, 0);
                acc[m] = __builtin_amdgcn_mfma_f32_16x16x32_bf16(a3, cur[3], acc[m], 0, 0, 0);
            }

            // tanh(p) = 1 - 2/(exp2(C2*p)+1);  sum w2*tanh = w2*(nval - 2*sum(rcp))
            float b1s = b1v * C2;
            float rsum = 0.f;
            #pragma unroll
            for (int m = 0; m < 4; ++m) {
                #pragma unroll
                for (int r = 0; r < 4; ++r) {
                    float exv = __builtin_amdgcn_exp2f(fmaf(C2, acc[m][r], b1s));
                    float rc  = __builtin_amdgcn_rcpf(exv + 1.f);
                    if (!full)
                        rc = (waveBase + m * 16 + lk * 4 + r < realEnd) ? rc : 0.f;
                    rsum += rc;
                }
            }
            partial = fmaf(w2v, fmaf(-2.f, rsum, fnval), partial);

            #pragma unroll
            for (int ks = 0; ks < 4; ++ks) cur[ks] = nxt[ks];
            b1v = b1n; w2v = w2n;
        }
    } else {
        __syncthreads();   // keep barrier uniform across the block
    }

    #pragma unroll
    for (int off = 32; off; off >>= 1)
        partial += __shfl_down(partial, off);
    if (lane == 0) red[wid] = partial;
    __syncthreads();
    if (t == 0)
        bpart[blockIdx.x] = red[0] + red[1] + red[2] + red[3];   // plain store
}

// K5: single block reduces block partials + analytic bias term.
__global__ void tnn_k5_reduce(const float* __restrict__ bpart, const int* __restrict__ counts,
                              const float* __restrict__ b2, float* __restrict__ out) {
    __shared__ float r[4];
    int t = threadIdx.x;
    float s = 0.f;
    for (int i = t; i < NTILES; i += 256) s += bpart[i];
    #pragma unroll
    for (int off = 32; off; off >>= 1)
        s += __shfl_down(s, off);
    if ((t & 63) == 0) r[t >> 6] = s;
    __syncthreads();
    if (t == 0) {
        float acc = r[0] + r[1] + r[2] + r[3];
        #pragma unroll
        for (int e = 0; e < N_ELEM; ++e)
            acc += (float)counts[e] * b2[e];   // b2 is [E,1]
        out[0] = acc;
    }
}

extern "C" void kernel_launch(void* const* d_in, const int* in_sizes, int n_in,
                              void* d_out, int out_size, void* d_ws, size_t ws_size,
                              hipStream_t stream) {
    const float* X   = (const float*)d_in[0];
    const int*   eid = (const int*)  d_in[1];
    const float* W1  = (const float*)d_in[2];
    const float* b1  = (const float*)d_in[3];
    const float* W2  = (const float*)d_in[4];
    const float* b2  = (const float*)d_in[5];
    float* out = (float*)d_out;

    char* ws = (char*)d_ws;
    unsigned short* W1t = (unsigned short*)ws;
    int*   counts    = (int*)  (ws + WS_COUNTS);
    int*   startArr  = (int*)  (ws + WS_START);
    float* bpart     = (float*)(ws + WS_BPART);
    int*   bcnt      = (int*)  (ws + WS_BCNT);
    int*   boff      = (int*)  (ws + WS_BOFF);
    int*   sortedIdx = (int*)  (ws + WS_SIDX);

    hipLaunchKernelGGL(tnn_k1_hist_w1t, dim3(K1_BLOCKS), dim3(256), 0, stream, eid, bcnt, W1, W1t);
    hipLaunchKernelGGL(tnn_k2_scan,     dim3(1),         dim3(256), 0, stream, bcnt, counts, startArr, boff);
    hipLaunchKernelGGL(tnn_k3_scatter,  dim3(K1_BLOCKS), dim3(256), 0, stream, eid, boff, sortedIdx);
    hipLaunchKernelGGL(tnn_k4_mlp,      dim3(NTILES),    dim3(256), 0, stream,
                       X, sortedIdx, startArr, counts, W1t, b1, W2, bpart);
    hipLaunchKernelGGL(tnn_k5_reduce,   dim3(1),         dim3(256), 0, stream, bpart, counts, b2, out);
}